// Round 9
// baseline (1234.215 us; speedup 1.0000x reference)
//
#include <hip/hip_runtime.h>
#include <hip/hip_fp16.h>
#include <hip/hip_cooperative_groups.h>

namespace cg = cooperative_groups;

#define S_FEAT 16
#define D_FEAT 8
#define E_FEAT 4
#define EDGE_IN 52   // E_FEAT + 2*S_FEAT + 2*D_FEAT
#define HIDDEN 16    // 2*D_FEAT
#define SCAN_CHUNK 2048
#define NSUB 8
#define MEGA_GRID 1024

typedef unsigned int uint4v __attribute__((ext_vector_type(4)));
typedef float float4v __attribute__((ext_vector_type(4)));

// ---------------------------------------------------------------------------
// helpers
// ---------------------------------------------------------------------------
__device__ __forceinline__ uint4v pack_rec(const float s[8], int row)
{
    int q[8];
#pragma unroll
    for (int i = 0; i < 8; ++i) {
        float v = fminf(fmaxf(s[i] * 2047.f, -2047.f), 2047.f);
        q[i] = (int)rintf(v) & 0xFFF;
    }
    uint4v r;
    r[0] = (unsigned)(q[0] | (q[1] << 12) | (q[2] << 24));
    r[1] = (unsigned)((q[2] >> 8) | (q[3] << 4) | (q[4] << 16) | (q[5] << 28));
    r[2] = (unsigned)((q[5] >> 4) | (q[6] << 8) | (q[7] << 20));
    r[3] = (unsigned)row;
    return r;
}

__device__ __forceinline__ float rec_s(uint4v r, int f)
{
    int off = f * 12;
    unsigned lo = off < 32 ? r[0] : (off < 64 ? r[1] : r[2]);
    unsigned hi = off < 32 ? r[1] : (off < 64 ? r[2] : 0u);
    unsigned sh = (unsigned)off & 31u;
    unsigned long long both = ((unsigned long long)hi << 32) | lo;
    int q = ((int)((unsigned)(both >> sh) << 20)) >> 20;   // sext 12-bit
    return (float)q * (1.f / 2047.f);
}

__device__ __forceinline__ void unpack8h(uint4v w, float* dst)
{
#pragma unroll
    for (int i = 0; i < 4; ++i) {
        unsigned u = w[i];
        __half2 h = *reinterpret_cast<__half2*>(&u);
        float2 f = __half22float2(h);
        dst[2 * i] = f.x; dst[2 * i + 1] = f.y;
    }
}

// proj + out0 body for one node
__device__ __forceinline__ void proj_node(
    int n, const float* __restrict__ x_s, const float* __restrict__ x_d,
    const float* __restrict__ W1, const float* __restrict__ b1,
    const float* __restrict__ Wf0,
    __half* __restrict__ PRh, __half* __restrict__ PCh, float* __restrict__ out)
{
    float xs[S_FEAT], xd[D_FEAT];
    {
        const float4* p = (const float4*)(x_s + (size_t)n * S_FEAT);
#pragma unroll
        for (int q = 0; q < 4; ++q) {
            float4 v = p[q];
            xs[q * 4 + 0] = v.x; xs[q * 4 + 1] = v.y;
            xs[q * 4 + 2] = v.z; xs[q * 4 + 3] = v.w;
        }
        const float4* pd = (const float4*)(x_d + (size_t)n * D_FEAT);
        float4 a = pd[0], b = pd[1];
        xd[0] = a.x; xd[1] = a.y; xd[2] = a.z; xd[3] = a.w;
        xd[4] = b.x; xd[5] = b.y; xd[6] = b.z; xd[7] = b.w;
    }
    __half prh[HIDDEN], pch[HIDDEN];
#pragma unroll
    for (int i = 0; i < HIDDEN; ++i) {
        const float* w = W1 + i * EDGE_IN;
        float a = b1[i], c = 0.f;
#pragma unroll
        for (int j = 0; j < S_FEAT; ++j) {
            a = fmaf(xs[j], w[j], a);
            c = fmaf(xs[j], w[16 + j], c);
        }
#pragma unroll
        for (int j = 0; j < D_FEAT; ++j) {
            a = fmaf(xd[j], w[32 + j], a);
            c = fmaf(xd[j], w[40 + j], c);
        }
        prh[i] = __float2half_rn(a);
        pch[i] = __float2half_rn(c);
    }
    {
        uint4v* pr = (uint4v*)(PRh + (size_t)n * HIDDEN);
        uint4v* pc = (uint4v*)(PCh + (size_t)n * HIDDEN);
        pr[0] = *(uint4v*)&prh[0]; pr[1] = *(uint4v*)&prh[8];
        pc[0] = *(uint4v*)&pch[0]; pc[1] = *(uint4v*)&pch[8];
    }
    float o[D_FEAT];
#pragma unroll
    for (int i = 0; i < D_FEAT; ++i) {
        float acc = 0.f;
#pragma unroll
        for (int j = 0; j < D_FEAT; ++j)
            acc = fmaf(xd[j], Wf0[i * D_FEAT + j], acc);
        o[i] = acc;
    }
    float4* op = (float4*)(out + (size_t)n * D_FEAT);
    op[0] = make_float4(o[0], o[1], o[2], o[3]);
    op[1] = make_float4(o[4], o[5], o[6], o[7]);
}

// edge MLP via fp16 projection tables -> pack -> scatter to sorted position
__device__ __forceinline__ void edge_work(
    const __half* __restrict__ PRh, const __half* __restrict__ PCh,
    const float* __restrict__ edge_attr,
    const float* __restrict__ W1,
    const float* __restrict__ W2, const float* __restrict__ b2,
    int row, int col, int e,
    int* __restrict__ cursor, uint4v* __restrict__ recs)
{
    float pr[HIDDEN], pc[HIDDEN];
    {
        const uint4v* p = (const uint4v*)(PRh + (size_t)row * HIDDEN);
        const uint4v* c = (const uint4v*)(PCh + (size_t)col * HIDDEN);
        uint4v p0 = p[0], p1 = p[1], c0 = c[0], c1 = c[1];
        unpack8h(p0, pr); unpack8h(p1, pr + 8);
        unpack8h(c0, pc); unpack8h(c1, pc + 8);
    }
    float4v ea = __builtin_nontemporal_load(
        (const float4v*)(edge_attr + (size_t)e * E_FEAT));

    float h[HIDDEN];
#pragma unroll
    for (int i = 0; i < HIDDEN; ++i) {
        const float* w = W1 + i * EDGE_IN + 48;
        float acc = pr[i] + pc[i];
        acc = fmaf(ea[0], w[0], acc);
        acc = fmaf(ea[1], w[1], acc);
        acc = fmaf(ea[2], w[2], acc);
        acc = fmaf(ea[3], w[3], acc);
        h[i] = acc > 0.f ? acc : 0.f;
    }

    float s[D_FEAT];
    float nrm2 = 0.f;
#pragma unroll
    for (int i = 0; i < D_FEAT; ++i) {
        float acc = b2[i];
#pragma unroll
        for (int j = 0; j < HIDDEN; ++j)
            acc = fmaf(h[j], W2[i * HIDDEN + j], acc);
        s[i] = acc;
        nrm2 = fmaf(acc, acc, nrm2);
    }
    float nrm = sqrtf(nrm2);
    float inv = nrm > 0.f ? 1.f / nrm : 0.f;
#pragma unroll
    for (int i = 0; i < D_FEAT; ++i) s[i] *= inv;

    uint4v rec = pack_rec(s, row);
    int pos = atomicAdd(&cursor[col], 1);
    __builtin_nontemporal_store(rec, recs + pos);
}

// one CSR propagation sweep (grid-stride over nodes, 1 wave per node)
__device__ __forceinline__ void csr_phase(
    const float* __restrict__ out_in, float* __restrict__ out_out,
    const int* __restrict__ offsets, const uint4v* __restrict__ recs,
    const float* __restrict__ Wf, int N)
{
    int lane = threadIdx.x & 63;
    int wid = (blockIdx.x << 2) | (threadIdx.x >> 6);
    int nwaves = gridDim.x << 2;
    int e_sub = lane >> 3, f = lane & 7;
    for (int node = wid; node < N; node += nwaves) {
        int beg = offsets[node], end = offsets[node + 1];
        float outc = out_in[(size_t)node * 8 + f];
        float sc = outc;
        sc += __shfl_xor(sc, 1); sc += __shfl_xor(sc, 2); sc += __shfl_xor(sc, 4);
        bool mc = (sc != 0.f);
        float acc = 0.f;
        for (int base = beg; base < end; base += 8) {
            int e = base + e_sub;
            bool valid = e < end;
            uint4v rec = (uint4v)(0u);
            if (valid) rec = __builtin_nontemporal_load(recs + e);
            int row = (int)rec[3];
            float s = rec_s(rec, f);
            float outr = out_in[(size_t)row * 8 + f];
            float sr = outr;
            sr += __shfl_xor(sr, 1); sr += __shfl_xor(sr, 2); sr += __shfl_xor(sr, 4);
            acc += (mc || sr != 0.f) ? (outc - outr) * s : 0.f;
        }
        acc += __shfl_xor(acc, 8);
        acc += __shfl_xor(acc, 16);
        acc += __shfl_xor(acc, 32);
        float upd = 0.f;
#pragma unroll
        for (int j = 0; j < 8; ++j) {
            float aj = __shfl(acc, (lane & ~7) | j);
            upd = fmaf(Wf[f * 8 + j], aj, upd);
        }
        if (e_sub == 0)
            out_out[(size_t)node * 8 + f] = outc + upd;
    }
}

// ---------------------------------------------------------------------------
// THE mega kernel: whole pipeline, one cooperative launch.
// No early returns anywhere (grid.sync safety).
// ---------------------------------------------------------------------------
__global__ __launch_bounds__(256, 4) void mega_kernel(
    const int* __restrict__ ei, int E, int N,
    int* __restrict__ counts8, int* __restrict__ offsets,
    int* __restrict__ cursor, int* __restrict__ bsums,
    const float* __restrict__ x_s, const float* __restrict__ x_d,
    const float* __restrict__ edge_attr,
    const float* __restrict__ W1, const float* __restrict__ b1,
    const float* __restrict__ W2, const float* __restrict__ b2,
    const float* __restrict__ Wf0, const float* __restrict__ Wf1,
    const float* __restrict__ Wf2,
    __half* __restrict__ PRh, __half* __restrict__ PCh,
    float* __restrict__ out, float* __restrict__ bufA,
    uint4v* __restrict__ recs)
{
    cg::grid_group grid = cg::this_grid();
    const int tid = blockIdx.x * blockDim.x + threadIdx.x;
    const int nthr = gridDim.x * blockDim.x;
    const int NB = (N + SCAN_CHUNK - 1) / SCAN_CHUNK;
    __shared__ int sh[256];

    // P0: zero histogram
    for (int i = tid; i < NSUB * N; i += nthr) counts8[i] = 0;
    grid.sync();

    // P1: histogram of cols (8-way split to cut contention)
    for (int e = tid; e < E; e += nthr) {
        int col = __builtin_nontemporal_load(ei + E + e);
        atomicAdd(&counts8[(threadIdx.x & (NSUB - 1)) * N + col], 1);
    }
    grid.sync();

    // P2: per-chunk exclusive scan (block-parallel), chunk sums -> bsums
    for (int b = blockIdx.x; b < NB; b += gridDim.x) {
        int t = threadIdx.x;
        int base = b * SCAN_CHUNK + t * 8;
        int v[8];
        int run = 0;
#pragma unroll
        for (int j = 0; j < 8; ++j) {
            int c = 0;
            if (base + j < N) {
#pragma unroll
                for (int s8 = 0; s8 < NSUB; ++s8)
                    c += counts8[s8 * N + base + j];
            }
            v[j] = run;
            run += c;
        }
        sh[t] = run;
        __syncthreads();
#pragma unroll
        for (int st = 1; st < 256; st <<= 1) {
            int x = (t >= st) ? sh[t - st] : 0;
            __syncthreads();
            sh[t] += x;
            __syncthreads();
        }
        int excl = sh[t] - run;
        if (t == 255) bsums[b] = sh[255];
#pragma unroll
        for (int j = 0; j < 8; ++j)
            if (base + j < N) offsets[base + j] = excl + v[j];
        __syncthreads();   // protect sh reuse across b iterations
    }
    grid.sync();

    // P3: exclusive scan of chunk sums (block 0, wave 0)
    if (blockIdx.x == 0 && threadIdx.x < 64) {
        int lane = threadIdx.x;
        int carry = 0;
        for (int base = 0; base < NB; base += 64) {
            int i = base + lane;
            int orig = (i < NB) ? bsums[i] : 0;
            int v = orig;
#pragma unroll
            for (int st = 1; st < 64; st <<= 1) {
                int t2 = __shfl_up(v, st);
                if (lane >= st) v += t2;
            }
            if (i < NB) bsums[i] = carry + v - orig;
            carry += __shfl(v, 63);
        }
    }
    grid.sync();

    // P4: finalize offsets/cursor + per-node projections + out0
    for (int n = tid; n <= N; n += nthr) {
        if (n == N) { offsets[N] = E; continue; }
        int off2 = offsets[n] + bsums[n / SCAN_CHUNK];
        offsets[n] = off2;
        cursor[n]  = off2;
        proj_node(n, x_s, x_d, W1, b1, Wf0, PRh, PCh, out);
    }
    grid.sync();

    // P5: edge MLP + scatter to CSR position
    for (int e = tid; e < E; e += nthr) {
        int row = ei[e], col = ei[E + e];
        edge_work(PRh, PCh, edge_attr, W1, W2, b2, row, col, e, cursor, recs);
    }
    grid.sync();

    // P6/P7: two propagation sweeps (double-buffered)
    csr_phase(out, bufA, offsets, recs, Wf1, N);
    grid.sync();
    csr_phase(bufA, out, offsets, recs, Wf2, N);
}

// ---------------------------------------------------------------------------
// Fallback separate kernels (used if cooperative launch unavailable,
// and for tier-B/C small-ws paths).
// ---------------------------------------------------------------------------
__global__ __launch_bounds__(256) void zero_counts_kernel(int* __restrict__ counts, int M)
{
    int i = blockIdx.x * blockDim.x + threadIdx.x;
    if (i < M) counts[i] = 0;
}

__global__ __launch_bounds__(256) void hist_kernel(
    const int* __restrict__ ei, int E, int N, int* __restrict__ counts8)
{
    int e = blockIdx.x * blockDim.x + threadIdx.x;
    if (e >= E) return;
    int col = __builtin_nontemporal_load(ei + E + e);
    atomicAdd(&counts8[(threadIdx.x & (NSUB - 1)) * N + col], 1);
}

__global__ __launch_bounds__(256) void scan_local_kernel(
    const int* __restrict__ counts8, int* __restrict__ partial,
    int* __restrict__ blocksums, int N)
{
    __shared__ int sh[256];
    int b = blockIdx.x, t = threadIdx.x;
    int base = b * SCAN_CHUNK + t * 8;
    int v[8];
    int run = 0;
#pragma unroll
    for (int j = 0; j < 8; ++j) {
        int c = 0;
        if (base + j < N) {
#pragma unroll
            for (int s8 = 0; s8 < NSUB; ++s8)
                c += counts8[s8 * N + base + j];
        }
        v[j] = run;
        run += c;
    }
    sh[t] = run;
    __syncthreads();
#pragma unroll
    for (int st = 1; st < 256; st <<= 1) {
        int x = (t >= st) ? sh[t - st] : 0;
        __syncthreads();
        sh[t] += x;
        __syncthreads();
    }
    int excl = sh[t] - run;
    if (t == 255) blocksums[b] = sh[255];
#pragma unroll
    for (int j = 0; j < 8; ++j)
        if (base + j < N) partial[base + j] = excl + v[j];
}

__global__ __launch_bounds__(64) void scan_blk_kernel(int* __restrict__ bs, int NB)
{
    int lane = threadIdx.x;
    int carry = 0;
    for (int base = 0; base < NB; base += 64) {
        int i = base + lane;
        int orig = (i < NB) ? bs[i] : 0;
        int v = orig;
#pragma unroll
        for (int st = 1; st < 64; st <<= 1) {
            int t = __shfl_up(v, st);
            if (lane >= st) v += t;
        }
        if (i < NB) bs[i] = carry + v - orig;
        carry += __shfl(v, 63);
    }
}

__global__ __launch_bounds__(256) void proj_scan_kernel(
    int* __restrict__ offsets, int* __restrict__ cursor,
    const int* __restrict__ blocksums,
    const float* __restrict__ x_s, const float* __restrict__ x_d,
    const float* __restrict__ W1, const float* __restrict__ b1,
    const float* __restrict__ Wf0,
    __half* __restrict__ PRh, __half* __restrict__ PCh,
    float* __restrict__ out, int N, int E)
{
    int n = blockIdx.x * blockDim.x + threadIdx.x;
    if (n > N) return;
    if (n == N) { offsets[N] = E; return; }
    int off2 = offsets[n] + blocksums[n / SCAN_CHUNK];
    offsets[n] = off2;
    cursor[n]  = off2;
    proj_node(n, x_s, x_d, W1, b1, Wf0, PRh, PCh, out);
}

__global__ __launch_bounds__(256) void mlp_scatter_proj_kernel(
    const __half* __restrict__ PRh, const __half* __restrict__ PCh,
    const float* __restrict__ edge_attr,
    const float* __restrict__ W1,
    const float* __restrict__ W2, const float* __restrict__ b2,
    const int* __restrict__ ei, int E,
    int* __restrict__ cursor, uint4v* __restrict__ recs)
{
    int e = blockIdx.x * blockDim.x + threadIdx.x;
    if (e >= E) return;
    int row = ei[e], col = ei[E + e];
    edge_work(PRh, PCh, edge_attr, W1, W2, b2, row, col, e, cursor, recs);
}

__global__ __launch_bounds__(256) void csr_step_kernel(
    const float* __restrict__ out_in, float* __restrict__ out_out,
    const int* __restrict__ offsets, const uint4v* __restrict__ recs,
    const float* __restrict__ Wf, int N)
{
    int lane = threadIdx.x & 63;
    int node = blockIdx.x * 4 + (threadIdx.x >> 6);
    if (node >= N) return;
    int e_sub = lane >> 3, f = lane & 7;
    int beg = offsets[node], end = offsets[node + 1];
    float outc = out_in[(size_t)node * 8 + f];
    float sc = outc;
    sc += __shfl_xor(sc, 1); sc += __shfl_xor(sc, 2); sc += __shfl_xor(sc, 4);
    bool mc = (sc != 0.f);
    float acc = 0.f;
    for (int base = beg; base < end; base += 8) {
        int e = base + e_sub;
        bool valid = e < end;
        uint4v rec = (uint4v)(0u);
        if (valid) rec = __builtin_nontemporal_load(recs + e);
        int row = (int)rec[3];
        float s = rec_s(rec, f);
        float outr = out_in[(size_t)row * 8 + f];
        float sr = outr;
        sr += __shfl_xor(sr, 1); sr += __shfl_xor(sr, 2); sr += __shfl_xor(sr, 4);
        acc += (mc || sr != 0.f) ? (outc - outr) * s : 0.f;
    }
    acc += __shfl_xor(acc, 8);
    acc += __shfl_xor(acc, 16);
    acc += __shfl_xor(acc, 32);
    float upd = 0.f;
#pragma unroll
    for (int j = 0; j < 8; ++j) {
        float aj = __shfl(acc, (lane & ~7) | j);
        upd = fmaf(Wf[f * 8 + j], aj, upd);
    }
    if (e_sub == 0)
        out_out[(size_t)node * 8 + f] = outc + upd;
}

// ------- tier B/C pieces (full per-edge MLP, atomic path) -------
__device__ __forceinline__ void mlp_sij(
    const float* __restrict__ x_s, const float* __restrict__ x_d,
    const float* __restrict__ edge_attr,
    const float* __restrict__ W1, const float* __restrict__ b1,
    const float* __restrict__ W2, const float* __restrict__ b2,
    int row, int col, int e, float s[D_FEAT])
{
    float in[EDGE_IN];
    {
        const float4* p = (const float4*)(x_s + (size_t)row * S_FEAT);
#pragma unroll
        for (int q = 0; q < 4; ++q) {
            float4 v = p[q];
            in[q * 4 + 0] = v.x; in[q * 4 + 1] = v.y;
            in[q * 4 + 2] = v.z; in[q * 4 + 3] = v.w;
        }
    }
    {
        const float4* p = (const float4*)(x_s + (size_t)col * S_FEAT);
#pragma unroll
        for (int q = 0; q < 4; ++q) {
            float4 v = p[q];
            in[16 + q * 4 + 0] = v.x; in[16 + q * 4 + 1] = v.y;
            in[16 + q * 4 + 2] = v.z; in[16 + q * 4 + 3] = v.w;
        }
    }
    {
        const float4* p = (const float4*)(x_d + (size_t)row * D_FEAT);
#pragma unroll
        for (int q = 0; q < 2; ++q) {
            float4 v = p[q];
            in[32 + q * 4 + 0] = v.x; in[32 + q * 4 + 1] = v.y;
            in[32 + q * 4 + 2] = v.z; in[32 + q * 4 + 3] = v.w;
        }
    }
    {
        const float4* p = (const float4*)(x_d + (size_t)col * D_FEAT);
#pragma unroll
        for (int q = 0; q < 2; ++q) {
            float4 v = p[q];
            in[40 + q * 4 + 0] = v.x; in[40 + q * 4 + 1] = v.y;
            in[40 + q * 4 + 2] = v.z; in[40 + q * 4 + 3] = v.w;
        }
    }
    {
        float4 v = *(const float4*)(edge_attr + (size_t)e * E_FEAT);
        in[48] = v.x; in[49] = v.y; in[50] = v.z; in[51] = v.w;
    }
    float h[HIDDEN];
#pragma unroll
    for (int i = 0; i < HIDDEN; ++i) {
        float acc = b1[i];
#pragma unroll
        for (int j = 0; j < EDGE_IN; ++j)
            acc = fmaf(in[j], W1[i * EDGE_IN + j], acc);
        h[i] = acc > 0.f ? acc : 0.f;
    }
    float nrm2 = 0.f;
#pragma unroll
    for (int i = 0; i < D_FEAT; ++i) {
        float acc = b2[i];
#pragma unroll
        for (int j = 0; j < HIDDEN; ++j)
            acc = fmaf(h[j], W2[i * HIDDEN + j], acc);
        s[i] = acc;
        nrm2 = fmaf(acc, acc, nrm2);
    }
    float nrm = sqrtf(nrm2);
    float inv = nrm > 0.f ? 1.f / nrm : 0.f;
#pragma unroll
    for (int i = 0; i < D_FEAT; ++i) s[i] *= inv;
}

__global__ __launch_bounds__(256) void mlp_scatter_direct_kernel(
    const float* __restrict__ x_s, const float* __restrict__ x_d,
    const float* __restrict__ edge_attr,
    const float* __restrict__ W1, const float* __restrict__ b1,
    const float* __restrict__ W2, const float* __restrict__ b2,
    const int* __restrict__ ei, int E,
    int* __restrict__ cursor, uint4v* __restrict__ recs)
{
    int e = blockIdx.x * blockDim.x + threadIdx.x;
    if (e >= E) return;
    int row = ei[e], col = ei[E + e];
    float s[D_FEAT];
    mlp_sij(x_s, x_d, edge_attr, W1, b1, W2, b2, row, col, e, s);
    uint4v rec = pack_rec(s, row);
    int pos = atomicAdd(&cursor[col], 1);
    __builtin_nontemporal_store(rec, recs + pos);
}

__global__ __launch_bounds__(256) void scan_add_kernel(
    int* __restrict__ offsets, int* __restrict__ cursor,
    const int* __restrict__ blocksums, int N, int E)
{
    int i = blockIdx.x * blockDim.x + threadIdx.x;
    if (i < N) {
        int off2 = offsets[i] + blocksums[i / SCAN_CHUNK];
        offsets[i] = off2;
        cursor[i]  = off2;
    } else if (i == N) {
        offsets[N] = E;
    }
}

__global__ __launch_bounds__(256) void node_init_kernel(
    const float* __restrict__ x_d, const float* __restrict__ Wf0,
    float* __restrict__ out, int N)
{
    int n = blockIdx.x * blockDim.x + threadIdx.x;
    if (n >= N) return;
    float xd[D_FEAT];
    const float4* p = (const float4*)(x_d + (size_t)n * D_FEAT);
    float4 a = p[0], b = p[1];
    xd[0] = a.x; xd[1] = a.y; xd[2] = a.z; xd[3] = a.w;
    xd[4] = b.x; xd[5] = b.y; xd[6] = b.z; xd[7] = b.w;
    float o[D_FEAT];
#pragma unroll
    for (int i = 0; i < D_FEAT; ++i) {
        float acc = 0.f;
#pragma unroll
        for (int j = 0; j < D_FEAT; ++j)
            acc = fmaf(xd[j], Wf0[i * D_FEAT + j], acc);
        o[i] = acc;
    }
    float4* op = (float4*)(out + (size_t)n * D_FEAT);
    op[0] = make_float4(o[0], o[1], o[2], o[3]);
    op[1] = make_float4(o[4], o[5], o[6], o[7]);
}

__global__ __launch_bounds__(256) void fb_node_init_kernel(
    const float* __restrict__ x_d, const float* __restrict__ Wf0,
    float* __restrict__ out, float* __restrict__ scattered, int N)
{
    int n = blockIdx.x * blockDim.x + threadIdx.x;
    if (n >= N) return;
    float xd[D_FEAT];
    const float4* p = (const float4*)(x_d + (size_t)n * D_FEAT);
    float4 a = p[0], b = p[1];
    xd[0] = a.x; xd[1] = a.y; xd[2] = a.z; xd[3] = a.w;
    xd[4] = b.x; xd[5] = b.y; xd[6] = b.z; xd[7] = b.w;
    float o[D_FEAT];
#pragma unroll
    for (int i = 0; i < D_FEAT; ++i) {
        float acc = 0.f;
#pragma unroll
        for (int j = 0; j < D_FEAT; ++j)
            acc = fmaf(xd[j], Wf0[i * D_FEAT + j], acc);
        o[i] = acc;
    }
    float4* op = (float4*)(out + (size_t)n * D_FEAT);
    op[0] = make_float4(o[0], o[1], o[2], o[3]);
    op[1] = make_float4(o[4], o[5], o[6], o[7]);
    float4* sp = (float4*)(scattered + (size_t)n * D_FEAT);
    sp[0] = make_float4(0.f, 0.f, 0.f, 0.f);
    sp[1] = make_float4(0.f, 0.f, 0.f, 0.f);
}

__global__ __launch_bounds__(256) void fb_edge_step_kernel(
    const float* __restrict__ x_s, const float* __restrict__ x_d,
    const float* __restrict__ edge_attr,
    const float* __restrict__ W1, const float* __restrict__ b1,
    const float* __restrict__ W2, const float* __restrict__ b2,
    const float* __restrict__ out,
    const int* __restrict__ ei, int E, float* __restrict__ scattered)
{
    int e = blockIdx.x * blockDim.x + threadIdx.x;
    if (e >= E) return;
    int row = ei[e], col = ei[E + e];
    const float4* pr = (const float4*)(out + (size_t)row * D_FEAT);
    const float4* pc = (const float4*)(out + (size_t)col * D_FEAT);
    float4 r0 = pr[0], r1 = pr[1], c0 = pc[0], c1 = pc[1];
    float srow = r0.x + r0.y + r0.z + r0.w + r1.x + r1.y + r1.z + r1.w;
    float scol = c0.x + c0.y + c0.z + c0.w + c1.x + c1.y + c1.z + c1.w;
    if (srow == 0.f && scol == 0.f) return;
    float s[D_FEAT];
    mlp_sij(x_s, x_d, edge_attr, W1, b1, W2, b2, row, col, e, s);
    float* dst = scattered + (size_t)col * D_FEAT;
    atomicAdd(dst + 0, (c0.x - r0.x) * s[0]);
    atomicAdd(dst + 1, (c0.y - r0.y) * s[1]);
    atomicAdd(dst + 2, (c0.z - r0.z) * s[2]);
    atomicAdd(dst + 3, (c0.w - r0.w) * s[3]);
    atomicAdd(dst + 4, (c1.x - r1.x) * s[4]);
    atomicAdd(dst + 5, (c1.y - r1.y) * s[5]);
    atomicAdd(dst + 6, (c1.z - r1.z) * s[6]);
    atomicAdd(dst + 7, (c1.w - r1.w) * s[7]);
}

__global__ __launch_bounds__(256) void fb_node_update_kernel(
    float* __restrict__ out, float* __restrict__ scattered,
    const float* __restrict__ Wf, int N)
{
    int n = blockIdx.x * blockDim.x + threadIdx.x;
    if (n >= N) return;
    float sc[D_FEAT];
    float4* sp = (float4*)(scattered + (size_t)n * D_FEAT);
    float4 a = sp[0], b = sp[1];
    sc[0] = a.x; sc[1] = a.y; sc[2] = a.z; sc[3] = a.w;
    sc[4] = b.x; sc[5] = b.y; sc[6] = b.z; sc[7] = b.w;
    sp[0] = make_float4(0.f, 0.f, 0.f, 0.f);
    sp[1] = make_float4(0.f, 0.f, 0.f, 0.f);
    float4* op = (float4*)(out + (size_t)n * D_FEAT);
    float4 o0 = op[0], o1 = op[1];
    float o[D_FEAT] = {o0.x, o0.y, o0.z, o0.w, o1.x, o1.y, o1.z, o1.w};
#pragma unroll
    for (int i = 0; i < D_FEAT; ++i) {
        float acc = 0.f;
#pragma unroll
        for (int j = 0; j < D_FEAT; ++j)
            acc = fmaf(sc[j], Wf[i * D_FEAT + j], acc);
        o[i] += acc;
    }
    op[0] = make_float4(o[0], o[1], o[2], o[3]);
    op[1] = make_float4(o[4], o[5], o[6], o[7]);
}

// ---------------------------------------------------------------------------
extern "C" void kernel_launch(void* const* d_in, const int* in_sizes, int n_in,
                              void* d_out, int out_size, void* d_ws, size_t ws_size,
                              hipStream_t stream) {
    const float* x_s       = (const float*)d_in[0];
    const float* x_d       = (const float*)d_in[1];
    const float* edge_attr = (const float*)d_in[2];
    const float* W1        = (const float*)d_in[3];
    const float* b1        = (const float*)d_in[4];
    const float* W2        = (const float*)d_in[5];
    const float* b2        = (const float*)d_in[6];
    const float* Wf0       = (const float*)d_in[7];
    const float* Wf1       = (const float*)d_in[8];
    const float* Wf2       = (const float*)d_in[9];
    const int*   ei        = (const int*)d_in[10];

    int N = in_sizes[1] / D_FEAT;
    int E = in_sizes[10] / 2;

    float* out = (float*)d_out;

    // ---- workspace layout ----
    size_t off = 0;
    auto carve = [&](size_t bytes) { size_t p = off; off = (off + bytes + 255) & ~255ULL; return p; };
    size_t o_counts  = carve((size_t)NSUB * N * 4);
    size_t o_offsets = carve((size_t)(N + 1) * 4);
    size_t o_cursor  = carve((size_t)(N + 1) * 4);
    size_t o_bsums   = carve(256 * 4);
    size_t o_bufA    = carve((size_t)N * D_FEAT * 4);
    size_t o_recs    = carve((size_t)E * 16);
    const size_t need_base = off;                       // tier B
    size_t o_PR      = carve((size_t)N * HIDDEN * 2);   // fp16
    size_t o_PC      = carve((size_t)N * HIDDEN * 2);   // fp16
    const size_t need_full = off;                       // tier A

    dim3 blk(256);
    dim3 gE((E + 255) / 256);
    dim3 gN((N + 255) / 256);

    if (ws_size >= need_base) {
        char* ws = (char*)d_ws;
        int*   counts8 = (int*)(ws + o_counts);
        int*   offsets = (int*)(ws + o_offsets);
        int*   cursor  = (int*)(ws + o_cursor);
        int*   bsums   = (int*)(ws + o_bsums);
        float* bufA    = (float*)(ws + o_bufA);
        uint4v* recs   = (uint4v*)(ws + o_recs);

        const int NB = (N + SCAN_CHUNK - 1) / SCAN_CHUNK;

        if (ws_size >= need_full) {
            __half* PRh = (__half*)(ws + o_PR);
            __half* PCh = (__half*)(ws + o_PC);

            // primary: one cooperative launch for the whole pipeline
            void* args[] = {
                (void*)&ei, (void*)&E, (void*)&N,
                (void*)&counts8, (void*)&offsets, (void*)&cursor, (void*)&bsums,
                (void*)&x_s, (void*)&x_d, (void*)&edge_attr,
                (void*)&W1, (void*)&b1, (void*)&W2, (void*)&b2,
                (void*)&Wf0, (void*)&Wf1, (void*)&Wf2,
                (void*)&PRh, (void*)&PCh,
                (void*)&out, (void*)&bufA, (void*)&recs
            };
            hipError_t cerr = hipLaunchCooperativeKernel(
                (const void*)mega_kernel, dim3(MEGA_GRID), blk, args, 0, stream);
            if (cerr == hipSuccess) return;

            // fallback: proven separate-kernel pipeline
            zero_counts_kernel<<<dim3((NSUB * N + 255) / 256), blk, 0, stream>>>(counts8, NSUB * N);
            hist_kernel<<<gE, blk, 0, stream>>>(ei, E, N, counts8);
            scan_local_kernel<<<dim3(NB), blk, 0, stream>>>(counts8, offsets, bsums, N);
            scan_blk_kernel<<<dim3(1), dim3(64), 0, stream>>>(bsums, NB);
            proj_scan_kernel<<<dim3((N + 256) / 256), blk, 0, stream>>>(
                offsets, cursor, bsums, x_s, x_d, W1, b1, Wf0, PRh, PCh, out, N, E);
            mlp_scatter_proj_kernel<<<gE, blk, 0, stream>>>(
                PRh, PCh, edge_attr, W1, W2, b2, ei, E, cursor, recs);
            dim3 gC((N + 3) / 4);
            csr_step_kernel<<<gC, blk, 0, stream>>>(out, bufA, offsets, recs, Wf1, N);
            csr_step_kernel<<<gC, blk, 0, stream>>>(bufA, out, offsets, recs, Wf2, N);
        } else {
            // tier B: no projection tables
            zero_counts_kernel<<<dim3((NSUB * N + 255) / 256), blk, 0, stream>>>(counts8, NSUB * N);
            hist_kernel<<<gE, blk, 0, stream>>>(ei, E, N, counts8);
            scan_local_kernel<<<dim3(NB), blk, 0, stream>>>(counts8, offsets, bsums, N);
            scan_blk_kernel<<<dim3(1), dim3(64), 0, stream>>>(bsums, NB);
            scan_add_kernel<<<dim3((N + 256) / 256), blk, 0, stream>>>(offsets, cursor, bsums, N, E);
            node_init_kernel<<<gN, blk, 0, stream>>>(x_d, Wf0, out, N);
            mlp_scatter_direct_kernel<<<gE, blk, 0, stream>>>(
                x_s, x_d, edge_attr, W1, b1, W2, b2, ei, E, cursor, recs);
            dim3 gC((N + 3) / 4);
            csr_step_kernel<<<gC, blk, 0, stream>>>(out, bufA, offsets, recs, Wf1, N);
            csr_step_kernel<<<gC, blk, 0, stream>>>(bufA, out, offsets, recs, Wf2, N);
        }
    } else {
        // tier C: fused atomic path, needs only N*8 floats
        float* scattered = (float*)d_ws;
        fb_node_init_kernel<<<gN, blk, 0, stream>>>(x_d, Wf0, out, scattered, N);
        for (int k = 0; k < 2; ++k) {
            const float* Wfk = (k == 0) ? Wf1 : Wf2;
            fb_edge_step_kernel<<<gE, blk, 0, stream>>>(
                x_s, x_d, edge_attr, W1, b1, W2, b2, out, ei, E, scattered);
            fb_node_update_kernel<<<gN, blk, 0, stream>>>(out, scattered, Wfk, N);
        }
    }
}

// Round 10
// 372.825 us; speedup vs baseline: 3.3104x; 3.3104x over previous
//
#include <hip/hip_runtime.h>
#include <hip/hip_fp16.h>

#define S_FEAT 16
#define D_FEAT 8
#define E_FEAT 4
#define EDGE_IN 52   // E_FEAT + 2*S_FEAT + 2*D_FEAT
#define HIDDEN 16    // 2*D_FEAT
#define SCAN_CHUNK 2048
#define NSUB 8

typedef unsigned int uint4v __attribute__((ext_vector_type(4)));
typedef float float4v __attribute__((ext_vector_type(4)));

// ---------------------------------------------------------------------------
// helpers
// ---------------------------------------------------------------------------
__device__ __forceinline__ uint4v pack_rec(const float s[8], int row)
{
    int q[8];
#pragma unroll
    for (int i = 0; i < 8; ++i) {
        float v = fminf(fmaxf(s[i] * 2047.f, -2047.f), 2047.f);
        q[i] = (int)rintf(v) & 0xFFF;
    }
    uint4v r;
    r[0] = (unsigned)(q[0] | (q[1] << 12) | (q[2] << 24));
    r[1] = (unsigned)((q[2] >> 8) | (q[3] << 4) | (q[4] << 16) | (q[5] << 28));
    r[2] = (unsigned)((q[5] >> 4) | (q[6] << 8) | (q[7] << 20));
    r[3] = (unsigned)row;
    return r;
}

__device__ __forceinline__ float rec_s(uint4v r, int f)
{
    int off = f * 12;
    unsigned lo = off < 32 ? r[0] : (off < 64 ? r[1] : r[2]);
    unsigned hi = off < 32 ? r[1] : (off < 64 ? r[2] : 0u);
    unsigned sh = (unsigned)off & 31u;
    unsigned long long both = ((unsigned long long)hi << 32) | lo;
    int q = ((int)((unsigned)(both >> sh) << 20)) >> 20;   // sext 12-bit
    return (float)q * (1.f / 2047.f);
}

__device__ __forceinline__ void unpack8h(uint4v w, float* dst)
{
#pragma unroll
    for (int i = 0; i < 4; ++i) {
        unsigned u = w[i];
        __half2 h = *reinterpret_cast<__half2*>(&u);
        float2 f = __half22float2(h);
        dst[2 * i] = f.x; dst[2 * i + 1] = f.y;
    }
}

// proj + out0 body for one node
__device__ __forceinline__ void proj_node(
    int n, const float* __restrict__ x_s, const float* __restrict__ x_d,
    const float* __restrict__ W1, const float* __restrict__ b1,
    const float* __restrict__ Wf0,
    __half* __restrict__ PRh, __half* __restrict__ PCh, float* __restrict__ out)
{
    float xs[S_FEAT], xd[D_FEAT];
    {
        const float4* p = (const float4*)(x_s + (size_t)n * S_FEAT);
#pragma unroll
        for (int q = 0; q < 4; ++q) {
            float4 v = p[q];
            xs[q * 4 + 0] = v.x; xs[q * 4 + 1] = v.y;
            xs[q * 4 + 2] = v.z; xs[q * 4 + 3] = v.w;
        }
        const float4* pd = (const float4*)(x_d + (size_t)n * D_FEAT);
        float4 a = pd[0], b = pd[1];
        xd[0] = a.x; xd[1] = a.y; xd[2] = a.z; xd[3] = a.w;
        xd[4] = b.x; xd[5] = b.y; xd[6] = b.z; xd[7] = b.w;
    }
    __half prh[HIDDEN], pch[HIDDEN];
#pragma unroll
    for (int i = 0; i < HIDDEN; ++i) {
        const float* w = W1 + i * EDGE_IN;
        float a = b1[i], c = 0.f;
#pragma unroll
        for (int j = 0; j < S_FEAT; ++j) {
            a = fmaf(xs[j], w[j], a);
            c = fmaf(xs[j], w[16 + j], c);
        }
#pragma unroll
        for (int j = 0; j < D_FEAT; ++j) {
            a = fmaf(xd[j], w[32 + j], a);
            c = fmaf(xd[j], w[40 + j], c);
        }
        prh[i] = __float2half_rn(a);
        pch[i] = __float2half_rn(c);
    }
    {
        uint4v* pr = (uint4v*)(PRh + (size_t)n * HIDDEN);
        uint4v* pc = (uint4v*)(PCh + (size_t)n * HIDDEN);
        pr[0] = *(uint4v*)&prh[0]; pr[1] = *(uint4v*)&prh[8];
        pc[0] = *(uint4v*)&pch[0]; pc[1] = *(uint4v*)&pch[8];
    }
    float o[D_FEAT];
#pragma unroll
    for (int i = 0; i < D_FEAT; ++i) {
        float acc = 0.f;
#pragma unroll
        for (int j = 0; j < D_FEAT; ++j)
            acc = fmaf(xd[j], Wf0[i * D_FEAT + j], acc);
        o[i] = acc;
    }
    float4* op = (float4*)(out + (size_t)n * D_FEAT);
    op[0] = make_float4(o[0], o[1], o[2], o[3]);
    op[1] = make_float4(o[4], o[5], o[6], o[7]);
}

// edge MLP via fp16 projection tables -> pack -> scatter to sorted position
__device__ __forceinline__ void edge_work(
    const __half* __restrict__ PRh, const __half* __restrict__ PCh,
    const float* __restrict__ edge_attr,
    const float* __restrict__ W1,
    const float* __restrict__ W2, const float* __restrict__ b2,
    int row, int col, int e,
    int* __restrict__ cursor, uint4v* __restrict__ recs)
{
    float pr[HIDDEN], pc[HIDDEN];
    {
        const uint4v* p = (const uint4v*)(PRh + (size_t)row * HIDDEN);
        const uint4v* c = (const uint4v*)(PCh + (size_t)col * HIDDEN);
        uint4v p0 = p[0], p1 = p[1], c0 = c[0], c1 = c[1];
        unpack8h(p0, pr); unpack8h(p1, pr + 8);
        unpack8h(c0, pc); unpack8h(c1, pc + 8);
    }
    float4v ea = __builtin_nontemporal_load(
        (const float4v*)(edge_attr + (size_t)e * E_FEAT));

    float h[HIDDEN];
#pragma unroll
    for (int i = 0; i < HIDDEN; ++i) {
        const float* w = W1 + i * EDGE_IN + 48;
        float acc = pr[i] + pc[i];
        acc = fmaf(ea[0], w[0], acc);
        acc = fmaf(ea[1], w[1], acc);
        acc = fmaf(ea[2], w[2], acc);
        acc = fmaf(ea[3], w[3], acc);
        h[i] = acc > 0.f ? acc : 0.f;
    }

    float s[D_FEAT];
    float nrm2 = 0.f;
#pragma unroll
    for (int i = 0; i < D_FEAT; ++i) {
        float acc = b2[i];
#pragma unroll
        for (int j = 0; j < HIDDEN; ++j)
            acc = fmaf(h[j], W2[i * HIDDEN + j], acc);
        s[i] = acc;
        nrm2 = fmaf(acc, acc, nrm2);
    }
    float nrm = sqrtf(nrm2);
    float inv = nrm > 0.f ? 1.f / nrm : 0.f;
#pragma unroll
    for (int i = 0; i < D_FEAT; ++i) s[i] *= inv;

    uint4v rec = pack_rec(s, row);
    int pos = atomicAdd(&cursor[col], 1);
    __builtin_nontemporal_store(rec, recs + pos);
}

// ---------------------------------------------------------------------------
// hist: 8-way split histogram of cols
// ---------------------------------------------------------------------------
__global__ __launch_bounds__(256) void hist_kernel(
    const int* __restrict__ ei, int E, int N, int* __restrict__ counts8)
{
    int e = blockIdx.x * blockDim.x + threadIdx.x;
    if (e >= E) return;
    int col = __builtin_nontemporal_load(ei + E + e);
    atomicAdd(&counts8[(threadIdx.x & (NSUB - 1)) * N + col], 1);
}

// ---------------------------------------------------------------------------
// scan_local + fused last-block bsums scan (done counter, atomics for
// cross-XCD-safe publish of aggregates).
// ---------------------------------------------------------------------------
__global__ __launch_bounds__(256) void scan_local_kernel(
    const int* __restrict__ counts8, int* __restrict__ partial,
    int* __restrict__ bsums, int* __restrict__ done, int N, int NB)
{
    __shared__ int sh[256];
    __shared__ int amLast;
    int b = blockIdx.x, t = threadIdx.x;
    int base = b * SCAN_CHUNK + t * 8;
    int v[8];
    int run = 0;
#pragma unroll
    for (int j = 0; j < 8; ++j) {
        int c = 0;
        if (base + j < N) {
#pragma unroll
            for (int s8 = 0; s8 < NSUB; ++s8)
                c += counts8[s8 * N + base + j];
        }
        v[j] = run;
        run += c;
    }
    sh[t] = run;
    __syncthreads();
#pragma unroll
    for (int st = 1; st < 256; st <<= 1) {
        int x = (t >= st) ? sh[t - st] : 0;
        __syncthreads();
        sh[t] += x;
        __syncthreads();
    }
    int excl = sh[t] - run;
#pragma unroll
    for (int j = 0; j < 8; ++j)
        if (base + j < N) partial[base + j] = excl + v[j];

    // publish aggregate through the coherent path (atomic), then signal
    if (t == 255) atomicExch(&bsums[b], sh[255]);
    __threadfence();
    if (t == 0) amLast = (atomicAdd(done, 1) == NB - 1);
    __syncthreads();
    if (amLast && t < 64) {
        int lane = t;
        int carry = 0;
        for (int cb = 0; cb < NB; cb += 64) {
            int i = cb + lane;
            int orig = (i < NB) ? atomicAdd(&bsums[i], 0) : 0;  // coherent read
            int x = orig;
#pragma unroll
            for (int st = 1; st < 64; st <<= 1) {
                int y = __shfl_up(x, st);
                if (lane >= st) x += y;
            }
            if (i < NB) atomicExch(&bsums[i], carry + x - orig); // exclusive
            carry += __shfl(x, 63);
        }
    }
}

// ---------------------------------------------------------------------------
// fused: scan_add + per-node projections + out0  (tier A)
// ---------------------------------------------------------------------------
__global__ __launch_bounds__(256) void proj_scan_kernel(
    int* __restrict__ offsets, int* __restrict__ cursor,
    const int* __restrict__ blocksums,
    const float* __restrict__ x_s, const float* __restrict__ x_d,
    const float* __restrict__ W1, const float* __restrict__ b1,
    const float* __restrict__ Wf0,
    __half* __restrict__ PRh, __half* __restrict__ PCh,
    float* __restrict__ out, int N, int E)
{
    int n = blockIdx.x * blockDim.x + threadIdx.x;
    if (n > N) return;
    if (n == N) { offsets[N] = E; return; }
    int off2 = offsets[n] + blocksums[n / SCAN_CHUNK];
    offsets[n] = off2;
    cursor[n]  = off2;
    proj_node(n, x_s, x_d, W1, b1, Wf0, PRh, PCh, out);
}

// 1 edge per thread (R6-proven config: VGPR 24, occ ~64%)
__global__ __launch_bounds__(256) void mlp_scatter_proj_kernel(
    const __half* __restrict__ PRh, const __half* __restrict__ PCh,
    const float* __restrict__ edge_attr,
    const float* __restrict__ W1,
    const float* __restrict__ W2, const float* __restrict__ b2,
    const int* __restrict__ ei, int E,
    int* __restrict__ cursor, uint4v* __restrict__ recs)
{
    int e = blockIdx.x * blockDim.x + threadIdx.x;
    if (e >= E) return;
    int row = __builtin_nontemporal_load(ei + e);
    int col = __builtin_nontemporal_load(ei + E + e);
    edge_work(PRh, PCh, edge_attr, W1, W2, b2, row, col, e, cursor, recs);
}

// ---------------------------------------------------------------------------
// CSR segment-sum step, shuffle-derived masks. 1 wave/node.
// ---------------------------------------------------------------------------
__global__ __launch_bounds__(256) void csr_step_kernel(
    const float* __restrict__ out_in, float* __restrict__ out_out,
    const int* __restrict__ offsets, const uint4v* __restrict__ recs,
    const float* __restrict__ Wf, int N)
{
    int lane = threadIdx.x & 63;
    int node = blockIdx.x * 4 + (threadIdx.x >> 6);
    if (node >= N) return;
    int e_sub = lane >> 3, f = lane & 7;
    int beg = offsets[node], end = offsets[node + 1];
    float outc = out_in[(size_t)node * 8 + f];
    float sc = outc;
    sc += __shfl_xor(sc, 1); sc += __shfl_xor(sc, 2); sc += __shfl_xor(sc, 4);
    bool mc = (sc != 0.f);
    float acc = 0.f;
    for (int base = beg; base < end; base += 8) {
        int e = base + e_sub;
        bool valid = e < end;
        uint4v rec = (uint4v)(0u);
        if (valid) rec = __builtin_nontemporal_load(recs + e);
        int row = (int)rec[3];
        float s = rec_s(rec, f);
        float outr = out_in[(size_t)row * 8 + f];
        float sr = outr;
        sr += __shfl_xor(sr, 1); sr += __shfl_xor(sr, 2); sr += __shfl_xor(sr, 4);
        acc += (mc || sr != 0.f) ? (outc - outr) * s : 0.f;
    }
    acc += __shfl_xor(acc, 8);
    acc += __shfl_xor(acc, 16);
    acc += __shfl_xor(acc, 32);
    float upd = 0.f;
#pragma unroll
    for (int j = 0; j < 8; ++j) {
        float aj = __shfl(acc, (lane & ~7) | j);
        upd = fmaf(Wf[f * 8 + j], aj, upd);
    }
    if (e_sub == 0)
        out_out[(size_t)node * 8 + f] = outc + upd;
}

// ---------------------------------------------------------------------------
// tier B/C pieces
// ---------------------------------------------------------------------------
__device__ __forceinline__ void mlp_sij(
    const float* __restrict__ x_s, const float* __restrict__ x_d,
    const float* __restrict__ edge_attr,
    const float* __restrict__ W1, const float* __restrict__ b1,
    const float* __restrict__ W2, const float* __restrict__ b2,
    int row, int col, int e, float s[D_FEAT])
{
    float in[EDGE_IN];
    {
        const float4* p = (const float4*)(x_s + (size_t)row * S_FEAT);
#pragma unroll
        for (int q = 0; q < 4; ++q) {
            float4 v = p[q];
            in[q * 4 + 0] = v.x; in[q * 4 + 1] = v.y;
            in[q * 4 + 2] = v.z; in[q * 4 + 3] = v.w;
        }
    }
    {
        const float4* p = (const float4*)(x_s + (size_t)col * S_FEAT);
#pragma unroll
        for (int q = 0; q < 4; ++q) {
            float4 v = p[q];
            in[16 + q * 4 + 0] = v.x; in[16 + q * 4 + 1] = v.y;
            in[16 + q * 4 + 2] = v.z; in[16 + q * 4 + 3] = v.w;
        }
    }
    {
        const float4* p = (const float4*)(x_d + (size_t)row * D_FEAT);
#pragma unroll
        for (int q = 0; q < 2; ++q) {
            float4 v = p[q];
            in[32 + q * 4 + 0] = v.x; in[32 + q * 4 + 1] = v.y;
            in[32 + q * 4 + 2] = v.z; in[32 + q * 4 + 3] = v.w;
        }
    }
    {
        const float4* p = (const float4*)(x_d + (size_t)col * D_FEAT);
#pragma unroll
        for (int q = 0; q < 2; ++q) {
            float4 v = p[q];
            in[40 + q * 4 + 0] = v.x; in[40 + q * 4 + 1] = v.y;
            in[40 + q * 4 + 2] = v.z; in[40 + q * 4 + 3] = v.w;
        }
    }
    {
        float4 v = *(const float4*)(edge_attr + (size_t)e * E_FEAT);
        in[48] = v.x; in[49] = v.y; in[50] = v.z; in[51] = v.w;
    }
    float h[HIDDEN];
#pragma unroll
    for (int i = 0; i < HIDDEN; ++i) {
        float acc = b1[i];
#pragma unroll
        for (int j = 0; j < EDGE_IN; ++j)
            acc = fmaf(in[j], W1[i * EDGE_IN + j], acc);
        h[i] = acc > 0.f ? acc : 0.f;
    }
    float nrm2 = 0.f;
#pragma unroll
    for (int i = 0; i < D_FEAT; ++i) {
        float acc = b2[i];
#pragma unroll
        for (int j = 0; j < HIDDEN; ++j)
            acc = fmaf(h[j], W2[i * HIDDEN + j], acc);
        s[i] = acc;
        nrm2 = fmaf(acc, acc, nrm2);
    }
    float nrm = sqrtf(nrm2);
    float inv = nrm > 0.f ? 1.f / nrm : 0.f;
#pragma unroll
    for (int i = 0; i < D_FEAT; ++i) s[i] *= inv;
}

__global__ __launch_bounds__(256) void scan_add_kernel(
    int* __restrict__ offsets, int* __restrict__ cursor,
    const int* __restrict__ blocksums, int N, int E)
{
    int i = blockIdx.x * blockDim.x + threadIdx.x;
    if (i < N) {
        int off2 = offsets[i] + blocksums[i / SCAN_CHUNK];
        offsets[i] = off2;
        cursor[i]  = off2;
    } else if (i == N) {
        offsets[N] = E;
    }
}

__global__ __launch_bounds__(256) void node_init_kernel(
    const float* __restrict__ x_d, const float* __restrict__ Wf0,
    float* __restrict__ out, int N)
{
    int n = blockIdx.x * blockDim.x + threadIdx.x;
    if (n >= N) return;
    float xd[D_FEAT];
    const float4* p = (const float4*)(x_d + (size_t)n * D_FEAT);
    float4 a = p[0], b = p[1];
    xd[0] = a.x; xd[1] = a.y; xd[2] = a.z; xd[3] = a.w;
    xd[4] = b.x; xd[5] = b.y; xd[6] = b.z; xd[7] = b.w;
    float o[D_FEAT];
#pragma unroll
    for (int i = 0; i < D_FEAT; ++i) {
        float acc = 0.f;
#pragma unroll
        for (int j = 0; j < D_FEAT; ++j)
            acc = fmaf(xd[j], Wf0[i * D_FEAT + j], acc);
        o[i] = acc;
    }
    float4* op = (float4*)(out + (size_t)n * D_FEAT);
    op[0] = make_float4(o[0], o[1], o[2], o[3]);
    op[1] = make_float4(o[4], o[5], o[6], o[7]);
}

__global__ __launch_bounds__(256) void mlp_scatter_direct_kernel(
    const float* __restrict__ x_s, const float* __restrict__ x_d,
    const float* __restrict__ edge_attr,
    const float* __restrict__ W1, const float* __restrict__ b1,
    const float* __restrict__ W2, const float* __restrict__ b2,
    const int* __restrict__ ei, int E,
    int* __restrict__ cursor, uint4v* __restrict__ recs)
{
    int e = blockIdx.x * blockDim.x + threadIdx.x;
    if (e >= E) return;
    int row = ei[e], col = ei[E + e];
    float s[D_FEAT];
    mlp_sij(x_s, x_d, edge_attr, W1, b1, W2, b2, row, col, e, s);
    uint4v rec = pack_rec(s, row);
    int pos = atomicAdd(&cursor[col], 1);
    __builtin_nontemporal_store(rec, recs + pos);
}

__global__ __launch_bounds__(256) void fb_node_init_kernel(
    const float* __restrict__ x_d, const float* __restrict__ Wf0,
    float* __restrict__ out, float* __restrict__ scattered, int N)
{
    int n = blockIdx.x * blockDim.x + threadIdx.x;
    if (n >= N) return;
    float xd[D_FEAT];
    const float4* p = (const float4*)(x_d + (size_t)n * D_FEAT);
    float4 a = p[0], b = p[1];
    xd[0] = a.x; xd[1] = a.y; xd[2] = a.z; xd[3] = a.w;
    xd[4] = b.x; xd[5] = b.y; xd[6] = b.z; xd[7] = b.w;
    float o[D_FEAT];
#pragma unroll
    for (int i = 0; i < D_FEAT; ++i) {
        float acc = 0.f;
#pragma unroll
        for (int j = 0; j < D_FEAT; ++j)
            acc = fmaf(xd[j], Wf0[i * D_FEAT + j], acc);
        o[i] = acc;
    }
    float4* op = (float4*)(out + (size_t)n * D_FEAT);
    op[0] = make_float4(o[0], o[1], o[2], o[3]);
    op[1] = make_float4(o[4], o[5], o[6], o[7]);
    float4* sp = (float4*)(scattered + (size_t)n * D_FEAT);
    sp[0] = make_float4(0.f, 0.f, 0.f, 0.f);
    sp[1] = make_float4(0.f, 0.f, 0.f, 0.f);
}

__global__ __launch_bounds__(256) void fb_edge_step_kernel(
    const float* __restrict__ x_s, const float* __restrict__ x_d,
    const float* __restrict__ edge_attr,
    const float* __restrict__ W1, const float* __restrict__ b1,
    const float* __restrict__ W2, const float* __restrict__ b2,
    const float* __restrict__ out,
    const int* __restrict__ ei, int E, float* __restrict__ scattered)
{
    int e = blockIdx.x * blockDim.x + threadIdx.x;
    if (e >= E) return;
    int row = ei[e], col = ei[E + e];
    const float4* pr = (const float4*)(out + (size_t)row * D_FEAT);
    const float4* pc = (const float4*)(out + (size_t)col * D_FEAT);
    float4 r0 = pr[0], r1 = pr[1], c0 = pc[0], c1 = pc[1];
    float srow = r0.x + r0.y + r0.z + r0.w + r1.x + r1.y + r1.z + r1.w;
    float scol = c0.x + c0.y + c0.z + c0.w + c1.x + c1.y + c1.z + c1.w;
    if (srow == 0.f && scol == 0.f) return;
    float s[D_FEAT];
    mlp_sij(x_s, x_d, edge_attr, W1, b1, W2, b2, row, col, e, s);
    float* dst = scattered + (size_t)col * D_FEAT;
    atomicAdd(dst + 0, (c0.x - r0.x) * s[0]);
    atomicAdd(dst + 1, (c0.y - r0.y) * s[1]);
    atomicAdd(dst + 2, (c0.z - r0.z) * s[2]);
    atomicAdd(dst + 3, (c0.w - r0.w) * s[3]);
    atomicAdd(dst + 4, (c1.x - r1.x) * s[4]);
    atomicAdd(dst + 5, (c1.y - r1.y) * s[5]);
    atomicAdd(dst + 6, (c1.z - r1.z) * s[6]);
    atomicAdd(dst + 7, (c1.w - r1.w) * s[7]);
}

__global__ __launch_bounds__(256) void fb_node_update_kernel(
    float* __restrict__ out, float* __restrict__ scattered,
    const float* __restrict__ Wf, int N)
{
    int n = blockIdx.x * blockDim.x + threadIdx.x;
    if (n >= N) return;
    float sc[D_FEAT];
    float4* sp = (float4*)(scattered + (size_t)n * D_FEAT);
    float4 a = sp[0], b = sp[1];
    sc[0] = a.x; sc[1] = a.y; sc[2] = a.z; sc[3] = a.w;
    sc[4] = b.x; sc[5] = b.y; sc[6] = b.z; sc[7] = b.w;
    sp[0] = make_float4(0.f, 0.f, 0.f, 0.f);
    sp[1] = make_float4(0.f, 0.f, 0.f, 0.f);
    float4* op = (float4*)(out + (size_t)n * D_FEAT);
    float4 o0 = op[0], o1 = op[1];
    float o[D_FEAT] = {o0.x, o0.y, o0.z, o0.w, o1.x, o1.y, o1.z, o1.w};
#pragma unroll
    for (int i = 0; i < D_FEAT; ++i) {
        float acc = 0.f;
#pragma unroll
        for (int j = 0; j < D_FEAT; ++j)
            acc = fmaf(sc[j], Wf[i * D_FEAT + j], acc);
        o[i] += acc;
    }
    op[0] = make_float4(o[0], o[1], o[2], o[3]);
    op[1] = make_float4(o[4], o[5], o[6], o[7]);
}

// ---------------------------------------------------------------------------
extern "C" void kernel_launch(void* const* d_in, const int* in_sizes, int n_in,
                              void* d_out, int out_size, void* d_ws, size_t ws_size,
                              hipStream_t stream) {
    const float* x_s       = (const float*)d_in[0];
    const float* x_d       = (const float*)d_in[1];
    const float* edge_attr = (const float*)d_in[2];
    const float* W1        = (const float*)d_in[3];
    const float* b1        = (const float*)d_in[4];
    const float* W2        = (const float*)d_in[5];
    const float* b2        = (const float*)d_in[6];
    const float* Wf0       = (const float*)d_in[7];
    const float* Wf1       = (const float*)d_in[8];
    const float* Wf2       = (const float*)d_in[9];
    const int*   ei        = (const int*)d_in[10];

    int N = in_sizes[1] / D_FEAT;
    int E = in_sizes[10] / 2;

    float* out = (float*)d_out;

    // ---- workspace layout (counts8 + done first: zeroed by one memset) ----
    size_t off = 0;
    auto carve = [&](size_t bytes) { size_t p = off; off = (off + bytes + 255) & ~255ULL; return p; };
    size_t o_counts  = carve((size_t)NSUB * N * 4);
    size_t o_done    = carve(4);
    const size_t zero_len = off;                        // counts8 + done
    size_t o_offsets = carve((size_t)(N + 1) * 4);
    size_t o_cursor  = carve((size_t)(N + 1) * 4);
    size_t o_bsums   = carve(256 * 4);
    size_t o_bufA    = carve((size_t)N * D_FEAT * 4);
    size_t o_recs    = carve((size_t)E * 16);
    const size_t need_base = off;                       // tier B
    size_t o_PR      = carve((size_t)N * HIDDEN * 2);   // fp16
    size_t o_PC      = carve((size_t)N * HIDDEN * 2);   // fp16
    const size_t need_full = off;                       // tier A

    dim3 blk(256);
    dim3 gE((E + 255) / 256);
    dim3 gN((N + 255) / 256);

    if (ws_size >= need_base) {
        char* ws = (char*)d_ws;
        int*   counts8 = (int*)(ws + o_counts);
        int*   done    = (int*)(ws + o_done);
        int*   offsets = (int*)(ws + o_offsets);
        int*   cursor  = (int*)(ws + o_cursor);
        int*   bsums   = (int*)(ws + o_bsums);
        float* bufA    = (float*)(ws + o_bufA);
        uint4v* recs   = (uint4v*)(ws + o_recs);

        const int NB = (N + SCAN_CHUNK - 1) / SCAN_CHUNK;

        hipMemsetAsync(ws, 0, zero_len, stream);  // counts8 + done
        hist_kernel<<<gE, blk, 0, stream>>>(ei, E, N, counts8);
        scan_local_kernel<<<dim3(NB), blk, 0, stream>>>(
            counts8, offsets, bsums, done, N, NB);

        if (ws_size >= need_full) {
            __half* PRh = (__half*)(ws + o_PR);
            __half* PCh = (__half*)(ws + o_PC);
            proj_scan_kernel<<<dim3((N + 256) / 256), blk, 0, stream>>>(
                offsets, cursor, bsums, x_s, x_d, W1, b1, Wf0, PRh, PCh, out, N, E);
            mlp_scatter_proj_kernel<<<gE, blk, 0, stream>>>(
                PRh, PCh, edge_attr, W1, W2, b2, ei, E, cursor, recs);
        } else {
            scan_add_kernel<<<dim3((N + 256) / 256), blk, 0, stream>>>(
                offsets, cursor, bsums, N, E);
            node_init_kernel<<<gN, blk, 0, stream>>>(x_d, Wf0, out, N);
            mlp_scatter_direct_kernel<<<gE, blk, 0, stream>>>(
                x_s, x_d, edge_attr, W1, b1, W2, b2, ei, E, cursor, recs);
        }

        dim3 gC((N + 3) / 4);
        csr_step_kernel<<<gC, blk, 0, stream>>>(out, bufA, offsets, recs, Wf1, N);
        csr_step_kernel<<<gC, blk, 0, stream>>>(bufA, out, offsets, recs, Wf2, N);
    } else {
        // tier C: fused atomic path, needs only N*8 floats
        float* scattered = (float*)d_ws;
        fb_node_init_kernel<<<gN, blk, 0, stream>>>(x_d, Wf0, out, scattered, N);
        for (int k = 0; k < 2; ++k) {
            const float* Wfk = (k == 0) ? Wf1 : Wf2;
            fb_edge_step_kernel<<<gE, blk, 0, stream>>>(
                x_s, x_d, edge_attr, W1, b1, W2, b2, out, ei, E, scattered);
            fb_node_update_kernel<<<gN, blk, 0, stream>>>(out, scattered, Wfk, N);
        }
    }
}

// Round 11
// 367.861 us; speedup vs baseline: 3.3551x; 1.0135x over previous
//
#include <hip/hip_runtime.h>
#include <hip/hip_fp16.h>

#define S_FEAT 16
#define D_FEAT 8
#define E_FEAT 4
#define EDGE_IN 52   // E_FEAT + 2*S_FEAT + 2*D_FEAT
#define HIDDEN 16    // 2*D_FEAT
#define SCAN_CHUNK 2048
#define NSUB 8

typedef unsigned int uint4v __attribute__((ext_vector_type(4)));
typedef float float4v __attribute__((ext_vector_type(4)));
typedef int int4v __attribute__((ext_vector_type(4)));

// ---------------------------------------------------------------------------
// helpers
// ---------------------------------------------------------------------------
__device__ __forceinline__ uint4v pack_rec(const float s[8], int row)
{
    int q[8];
#pragma unroll
    for (int i = 0; i < 8; ++i) {
        float v = fminf(fmaxf(s[i] * 2047.f, -2047.f), 2047.f);
        q[i] = (int)rintf(v) & 0xFFF;
    }
    uint4v r;
    r[0] = (unsigned)(q[0] | (q[1] << 12) | (q[2] << 24));
    r[1] = (unsigned)((q[2] >> 8) | (q[3] << 4) | (q[4] << 16) | (q[5] << 28));
    r[2] = (unsigned)((q[5] >> 4) | (q[6] << 8) | (q[7] << 20));
    r[3] = (unsigned)row;
    return r;
}

__device__ __forceinline__ float rec_s(uint4v r, int f)
{
    int off = f * 12;
    unsigned lo = off < 32 ? r[0] : (off < 64 ? r[1] : r[2]);
    unsigned hi = off < 32 ? r[1] : (off < 64 ? r[2] : 0u);
    unsigned sh = (unsigned)off & 31u;
    unsigned long long both = ((unsigned long long)hi << 32) | lo;
    int q = ((int)((unsigned)(both >> sh) << 20)) >> 20;   // sext 12-bit
    return (float)q * (1.f / 2047.f);
}

__device__ __forceinline__ void unpack8h(uint4v w, float* dst)
{
#pragma unroll
    for (int i = 0; i < 4; ++i) {
        unsigned u = w[i];
        __half2 h = *reinterpret_cast<__half2*>(&u);
        float2 f = __half22float2(h);
        dst[2 * i] = f.x; dst[2 * i + 1] = f.y;
    }
}

// proj + out0 body for one node
__device__ __forceinline__ void proj_node(
    int n, const float* __restrict__ x_s, const float* __restrict__ x_d,
    const float* __restrict__ W1, const float* __restrict__ b1,
    const float* __restrict__ Wf0,
    __half* __restrict__ PRh, __half* __restrict__ PCh, float* __restrict__ out)
{
    float xs[S_FEAT], xd[D_FEAT];
    {
        const float4* p = (const float4*)(x_s + (size_t)n * S_FEAT);
#pragma unroll
        for (int q = 0; q < 4; ++q) {
            float4 v = p[q];
            xs[q * 4 + 0] = v.x; xs[q * 4 + 1] = v.y;
            xs[q * 4 + 2] = v.z; xs[q * 4 + 3] = v.w;
        }
        const float4* pd = (const float4*)(x_d + (size_t)n * D_FEAT);
        float4 a = pd[0], b = pd[1];
        xd[0] = a.x; xd[1] = a.y; xd[2] = a.z; xd[3] = a.w;
        xd[4] = b.x; xd[5] = b.y; xd[6] = b.z; xd[7] = b.w;
    }
    __half prh[HIDDEN], pch[HIDDEN];
#pragma unroll
    for (int i = 0; i < HIDDEN; ++i) {
        const float* w = W1 + i * EDGE_IN;
        float a = b1[i], c = 0.f;
#pragma unroll
        for (int j = 0; j < S_FEAT; ++j) {
            a = fmaf(xs[j], w[j], a);
            c = fmaf(xs[j], w[16 + j], c);
        }
#pragma unroll
        for (int j = 0; j < D_FEAT; ++j) {
            a = fmaf(xd[j], w[32 + j], a);
            c = fmaf(xd[j], w[40 + j], c);
        }
        prh[i] = __float2half_rn(a);
        pch[i] = __float2half_rn(c);
    }
    {
        uint4v* pr = (uint4v*)(PRh + (size_t)n * HIDDEN);
        uint4v* pc = (uint4v*)(PCh + (size_t)n * HIDDEN);
        pr[0] = *(uint4v*)&prh[0]; pr[1] = *(uint4v*)&prh[8];
        pc[0] = *(uint4v*)&pch[0]; pc[1] = *(uint4v*)&pch[8];
    }
    float o[D_FEAT];
#pragma unroll
    for (int i = 0; i < D_FEAT; ++i) {
        float acc = 0.f;
#pragma unroll
        for (int j = 0; j < D_FEAT; ++j)
            acc = fmaf(xd[j], Wf0[i * D_FEAT + j], acc);
        o[i] = acc;
    }
    float4* op = (float4*)(out + (size_t)n * D_FEAT);
    op[0] = make_float4(o[0], o[1], o[2], o[3]);
    op[1] = make_float4(o[4], o[5], o[6], o[7]);
}

// edge MLP via fp16 tables; pos precomputed (atomic hoisted to caller)
__device__ __forceinline__ void edge_work(
    const __half* __restrict__ PRh, const __half* __restrict__ PCh,
    const float* __restrict__ edge_attr,
    const float* __restrict__ W1,
    const float* __restrict__ W2, const float* __restrict__ b2,
    int row, int col, int e, int pos, uint4v* __restrict__ recs)
{
    float pr[HIDDEN], pc[HIDDEN];
    {
        const uint4v* p = (const uint4v*)(PRh + (size_t)row * HIDDEN);
        const uint4v* c = (const uint4v*)(PCh + (size_t)col * HIDDEN);
        uint4v p0 = p[0], p1 = p[1], c0 = c[0], c1 = c[1];
        unpack8h(p0, pr); unpack8h(p1, pr + 8);
        unpack8h(c0, pc); unpack8h(c1, pc + 8);
    }
    float4v ea = __builtin_nontemporal_load(
        (const float4v*)(edge_attr + (size_t)e * E_FEAT));

    float h[HIDDEN];
#pragma unroll
    for (int i = 0; i < HIDDEN; ++i) {
        const float* w = W1 + i * EDGE_IN + 48;
        float acc = pr[i] + pc[i];
        acc = fmaf(ea[0], w[0], acc);
        acc = fmaf(ea[1], w[1], acc);
        acc = fmaf(ea[2], w[2], acc);
        acc = fmaf(ea[3], w[3], acc);
        h[i] = acc > 0.f ? acc : 0.f;
    }

    float s[D_FEAT];
    float nrm2 = 0.f;
#pragma unroll
    for (int i = 0; i < D_FEAT; ++i) {
        float acc = b2[i];
#pragma unroll
        for (int j = 0; j < HIDDEN; ++j)
            acc = fmaf(h[j], W2[i * HIDDEN + j], acc);
        s[i] = acc;
        nrm2 = fmaf(acc, acc, nrm2);
    }
    float nrm = sqrtf(nrm2);
    float inv = nrm > 0.f ? 1.f / nrm : 0.f;
#pragma unroll
    for (int i = 0; i < D_FEAT; ++i) s[i] *= inv;

    uint4v rec = pack_rec(s, row);
    __builtin_nontemporal_store(rec, recs + pos);
}

// ---------------------------------------------------------------------------
// K1 (tier A): 4-edge histogram + node projections fused.
// Node compute hides under atomic latency.
// ---------------------------------------------------------------------------
__global__ __launch_bounds__(256) void hist_proj_kernel(
    const int* __restrict__ ei, int E, int N, int* __restrict__ counts8,
    const float* __restrict__ x_s, const float* __restrict__ x_d,
    const float* __restrict__ W1, const float* __restrict__ b1,
    const float* __restrict__ Wf0,
    __half* __restrict__ PRh, __half* __restrict__ PCh,
    float* __restrict__ out)
{
    int tid = blockIdx.x * blockDim.x + threadIdx.x;
    int sub = (threadIdx.x & (NSUB - 1)) * N;
    int e0 = tid * 4;
    if (e0 + 3 < E) {
        int4v c = __builtin_nontemporal_load((const int4v*)(ei + E + e0));
        atomicAdd(&counts8[sub + c[0]], 1);
        atomicAdd(&counts8[sub + c[1]], 1);
        atomicAdd(&counts8[sub + c[2]], 1);
        atomicAdd(&counts8[sub + c[3]], 1);
    } else {
        for (int e = e0; e < E; ++e)
            atomicAdd(&counts8[sub + ei[E + e]], 1);
    }
    if (tid < N)
        proj_node(tid, x_s, x_d, W1, b1, Wf0, PRh, PCh, out);
}

// tier-B plain histogram
__global__ __launch_bounds__(256) void hist_kernel(
    const int* __restrict__ ei, int E, int N, int* __restrict__ counts8)
{
    int e = blockIdx.x * blockDim.x + threadIdx.x;
    if (e >= E) return;
    int col = __builtin_nontemporal_load(ei + E + e);
    atomicAdd(&counts8[(threadIdx.x & (NSUB - 1)) * N + col], 1);
}

// ---------------------------------------------------------------------------
// K2: scan_local + fused last-block bsums scan (R10-proven)
// ---------------------------------------------------------------------------
__global__ __launch_bounds__(256) void scan_local_kernel(
    const int* __restrict__ counts8, int* __restrict__ partial,
    int* __restrict__ bsums, int* __restrict__ done, int N, int NB)
{
    __shared__ int sh[256];
    __shared__ int amLast;
    int b = blockIdx.x, t = threadIdx.x;
    int base = b * SCAN_CHUNK + t * 8;
    int v[8];
    int run = 0;
#pragma unroll
    for (int j = 0; j < 8; ++j) {
        int c = 0;
        if (base + j < N) {
#pragma unroll
            for (int s8 = 0; s8 < NSUB; ++s8)
                c += counts8[s8 * N + base + j];
        }
        v[j] = run;
        run += c;
    }
    sh[t] = run;
    __syncthreads();
#pragma unroll
    for (int st = 1; st < 256; st <<= 1) {
        int x = (t >= st) ? sh[t - st] : 0;
        __syncthreads();
        sh[t] += x;
        __syncthreads();
    }
    int excl = sh[t] - run;
#pragma unroll
    for (int j = 0; j < 8; ++j)
        if (base + j < N) partial[base + j] = excl + v[j];

    if (t == 255) atomicExch(&bsums[b], sh[255]);
    __threadfence();
    if (t == 0) amLast = (atomicAdd(done, 1) == NB - 1);
    __syncthreads();
    if (amLast && t < 64) {
        int lane = t;
        int carry = 0;
        for (int cb = 0; cb < NB; cb += 64) {
            int i = cb + lane;
            int orig = (i < NB) ? atomicAdd(&bsums[i], 0) : 0;
            int x = orig;
#pragma unroll
            for (int st = 1; st < 64; st <<= 1) {
                int y = __shfl_up(x, st);
                if (lane >= st) x += y;
            }
            if (i < NB) atomicExch(&bsums[i], carry + x - orig);
            carry += __shfl(x, 63);
        }
    }
}

// K3: finalize offsets + cursor
__global__ __launch_bounds__(256) void scan_add_kernel(
    int* __restrict__ offsets, int* __restrict__ cursor,
    const int* __restrict__ blocksums, int N, int E)
{
    int i = blockIdx.x * blockDim.x + threadIdx.x;
    if (i < N) {
        int off2 = offsets[i] + blocksums[i / SCAN_CHUNK];
        offsets[i] = off2;
        cursor[i]  = off2;
    } else if (i == N) {
        offsets[N] = E;
    }
}

// K4: edge MLP, atomic hoisted before gathers/compute
__global__ __launch_bounds__(256) void mlp_scatter_proj_kernel(
    const __half* __restrict__ PRh, const __half* __restrict__ PCh,
    const float* __restrict__ edge_attr,
    const float* __restrict__ W1,
    const float* __restrict__ W2, const float* __restrict__ b2,
    const int* __restrict__ ei, int E,
    int* __restrict__ cursor, uint4v* __restrict__ recs)
{
    int e = blockIdx.x * blockDim.x + threadIdx.x;
    if (e >= E) return;
    int row = __builtin_nontemporal_load(ei + e);
    int col = __builtin_nontemporal_load(ei + E + e);
    int pos = atomicAdd(&cursor[col], 1);   // overlap atomic with MLP below
    edge_work(PRh, PCh, edge_attr, W1, W2, b2, row, col, e, pos, recs);
}

// ---------------------------------------------------------------------------
// K5/K6: CSR segment-sum, unroll-2 software pipeline. 1 wave/node.
// ---------------------------------------------------------------------------
__global__ __launch_bounds__(256) void csr_step_kernel(
    const float* __restrict__ out_in, float* __restrict__ out_out,
    const int* __restrict__ offsets, const uint4v* __restrict__ recs,
    const float* __restrict__ Wf, int N)
{
    int lane = threadIdx.x & 63;
    int node = blockIdx.x * 4 + (threadIdx.x >> 6);
    if (node >= N) return;
    int e_sub = lane >> 3, f = lane & 7;
    int beg = offsets[node], end = offsets[node + 1];
    float outc = out_in[(size_t)node * 8 + f];
    float sc = outc;
    sc += __shfl_xor(sc, 1); sc += __shfl_xor(sc, 2); sc += __shfl_xor(sc, 4);
    bool mc = (sc != 0.f);
    float acc = 0.f;
    for (int base = beg; base < end; base += 16) {
        int e0 = base + e_sub;
        int e1 = base + 8 + e_sub;
        uint4v r0 = (uint4v)(0u), r1 = (uint4v)(0u);
        if (e0 < end) r0 = __builtin_nontemporal_load(recs + e0);
        if (e1 < end) r1 = __builtin_nontemporal_load(recs + e1);
        int row0 = (int)r0[3], row1 = (int)r1[3];
        float g0 = out_in[(size_t)row0 * 8 + f];   // both gathers issue together
        float g1 = out_in[(size_t)row1 * 8 + f];
        float s0 = rec_s(r0, f), s1 = rec_s(r1, f);
        float sr0 = g0;
        sr0 += __shfl_xor(sr0, 1); sr0 += __shfl_xor(sr0, 2); sr0 += __shfl_xor(sr0, 4);
        float sr1 = g1;
        sr1 += __shfl_xor(sr1, 1); sr1 += __shfl_xor(sr1, 2); sr1 += __shfl_xor(sr1, 4);
        acc += (mc || sr0 != 0.f) ? (outc - g0) * s0 : 0.f;
        acc += (mc || sr1 != 0.f) ? (outc - g1) * s1 : 0.f;
    }
    acc += __shfl_xor(acc, 8);
    acc += __shfl_xor(acc, 16);
    acc += __shfl_xor(acc, 32);
    float upd = 0.f;
#pragma unroll
    for (int j = 0; j < 8; ++j) {
        float aj = __shfl(acc, (lane & ~7) | j);
        upd = fmaf(Wf[f * 8 + j], aj, upd);
    }
    if (e_sub == 0)
        out_out[(size_t)node * 8 + f] = outc + upd;
}

// ---------------------------------------------------------------------------
// tier B/C pieces
// ---------------------------------------------------------------------------
__device__ __forceinline__ void mlp_sij(
    const float* __restrict__ x_s, const float* __restrict__ x_d,
    const float* __restrict__ edge_attr,
    const float* __restrict__ W1, const float* __restrict__ b1,
    const float* __restrict__ W2, const float* __restrict__ b2,
    int row, int col, int e, float s[D_FEAT])
{
    float in[EDGE_IN];
    {
        const float4* p = (const float4*)(x_s + (size_t)row * S_FEAT);
#pragma unroll
        for (int q = 0; q < 4; ++q) {
            float4 v = p[q];
            in[q * 4 + 0] = v.x; in[q * 4 + 1] = v.y;
            in[q * 4 + 2] = v.z; in[q * 4 + 3] = v.w;
        }
    }
    {
        const float4* p = (const float4*)(x_s + (size_t)col * S_FEAT);
#pragma unroll
        for (int q = 0; q < 4; ++q) {
            float4 v = p[q];
            in[16 + q * 4 + 0] = v.x; in[16 + q * 4 + 1] = v.y;
            in[16 + q * 4 + 2] = v.z; in[16 + q * 4 + 3] = v.w;
        }
    }
    {
        const float4* p = (const float4*)(x_d + (size_t)row * D_FEAT);
#pragma unroll
        for (int q = 0; q < 2; ++q) {
            float4 v = p[q];
            in[32 + q * 4 + 0] = v.x; in[32 + q * 4 + 1] = v.y;
            in[32 + q * 4 + 2] = v.z; in[32 + q * 4 + 3] = v.w;
        }
    }
    {
        const float4* p = (const float4*)(x_d + (size_t)col * D_FEAT);
#pragma unroll
        for (int q = 0; q < 2; ++q) {
            float4 v = p[q];
            in[40 + q * 4 + 0] = v.x; in[40 + q * 4 + 1] = v.y;
            in[40 + q * 4 + 2] = v.z; in[40 + q * 4 + 3] = v.w;
        }
    }
    {
        float4 v = *(const float4*)(edge_attr + (size_t)e * E_FEAT);
        in[48] = v.x; in[49] = v.y; in[50] = v.z; in[51] = v.w;
    }
    float h[HIDDEN];
#pragma unroll
    for (int i = 0; i < HIDDEN; ++i) {
        float acc = b1[i];
#pragma unroll
        for (int j = 0; j < EDGE_IN; ++j)
            acc = fmaf(in[j], W1[i * EDGE_IN + j], acc);
        h[i] = acc > 0.f ? acc : 0.f;
    }
    float nrm2 = 0.f;
#pragma unroll
    for (int i = 0; i < D_FEAT; ++i) {
        float acc = b2[i];
#pragma unroll
        for (int j = 0; j < HIDDEN; ++j)
            acc = fmaf(h[j], W2[i * HIDDEN + j], acc);
        s[i] = acc;
        nrm2 = fmaf(acc, acc, nrm2);
    }
    float nrm = sqrtf(nrm2);
    float inv = nrm > 0.f ? 1.f / nrm : 0.f;
#pragma unroll
    for (int i = 0; i < D_FEAT; ++i) s[i] *= inv;
}

__global__ __launch_bounds__(256) void node_init_kernel(
    const float* __restrict__ x_d, const float* __restrict__ Wf0,
    float* __restrict__ out, int N)
{
    int n = blockIdx.x * blockDim.x + threadIdx.x;
    if (n >= N) return;
    float xd[D_FEAT];
    const float4* p = (const float4*)(x_d + (size_t)n * D_FEAT);
    float4 a = p[0], b = p[1];
    xd[0] = a.x; xd[1] = a.y; xd[2] = a.z; xd[3] = a.w;
    xd[4] = b.x; xd[5] = b.y; xd[6] = b.z; xd[7] = b.w;
    float o[D_FEAT];
#pragma unroll
    for (int i = 0; i < D_FEAT; ++i) {
        float acc = 0.f;
#pragma unroll
        for (int j = 0; j < D_FEAT; ++j)
            acc = fmaf(xd[j], Wf0[i * D_FEAT + j], acc);
        o[i] = acc;
    }
    float4* op = (float4*)(out + (size_t)n * D_FEAT);
    op[0] = make_float4(o[0], o[1], o[2], o[3]);
    op[1] = make_float4(o[4], o[5], o[6], o[7]);
}

__global__ __launch_bounds__(256) void mlp_scatter_direct_kernel(
    const float* __restrict__ x_s, const float* __restrict__ x_d,
    const float* __restrict__ edge_attr,
    const float* __restrict__ W1, const float* __restrict__ b1,
    const float* __restrict__ W2, const float* __restrict__ b2,
    const int* __restrict__ ei, int E,
    int* __restrict__ cursor, uint4v* __restrict__ recs)
{
    int e = blockIdx.x * blockDim.x + threadIdx.x;
    if (e >= E) return;
    int row = ei[e], col = ei[E + e];
    int pos = atomicAdd(&cursor[col], 1);
    float s[D_FEAT];
    mlp_sij(x_s, x_d, edge_attr, W1, b1, W2, b2, row, col, e, s);
    uint4v rec = pack_rec(s, row);
    __builtin_nontemporal_store(rec, recs + pos);
}

__global__ __launch_bounds__(256) void fb_node_init_kernel(
    const float* __restrict__ x_d, const float* __restrict__ Wf0,
    float* __restrict__ out, float* __restrict__ scattered, int N)
{
    int n = blockIdx.x * blockDim.x + threadIdx.x;
    if (n >= N) return;
    float xd[D_FEAT];
    const float4* p = (const float4*)(x_d + (size_t)n * D_FEAT);
    float4 a = p[0], b = p[1];
    xd[0] = a.x; xd[1] = a.y; xd[2] = a.z; xd[3] = a.w;
    xd[4] = b.x; xd[5] = b.y; xd[6] = b.z; xd[7] = b.w;
    float o[D_FEAT];
#pragma unroll
    for (int i = 0; i < D_FEAT; ++i) {
        float acc = 0.f;
#pragma unroll
        for (int j = 0; j < D_FEAT; ++j)
            acc = fmaf(xd[j], Wf0[i * D_FEAT + j], acc);
        o[i] = acc;
    }
    float4* op = (float4*)(out + (size_t)n * D_FEAT);
    op[0] = make_float4(o[0], o[1], o[2], o[3]);
    op[1] = make_float4(o[4], o[5], o[6], o[7]);
    float4* sp = (float4*)(scattered + (size_t)n * D_FEAT);
    sp[0] = make_float4(0.f, 0.f, 0.f, 0.f);
    sp[1] = make_float4(0.f, 0.f, 0.f, 0.f);
}

__global__ __launch_bounds__(256) void fb_edge_step_kernel(
    const float* __restrict__ x_s, const float* __restrict__ x_d,
    const float* __restrict__ edge_attr,
    const float* __restrict__ W1, const float* __restrict__ b1,
    const float* __restrict__ W2, const float* __restrict__ b2,
    const float* __restrict__ out,
    const int* __restrict__ ei, int E, float* __restrict__ scattered)
{
    int e = blockIdx.x * blockDim.x + threadIdx.x;
    if (e >= E) return;
    int row = ei[e], col = ei[E + e];
    const float4* pr = (const float4*)(out + (size_t)row * D_FEAT);
    const float4* pc = (const float4*)(out + (size_t)col * D_FEAT);
    float4 r0 = pr[0], r1 = pr[1], c0 = pc[0], c1 = pc[1];
    float srow = r0.x + r0.y + r0.z + r0.w + r1.x + r1.y + r1.z + r1.w;
    float scol = c0.x + c0.y + c0.z + c0.w + c1.x + c1.y + c1.z + c1.w;
    if (srow == 0.f && scol == 0.f) return;
    float s[D_FEAT];
    mlp_sij(x_s, x_d, edge_attr, W1, b1, W2, b2, row, col, e, s);
    float* dst = scattered + (size_t)col * D_FEAT;
    atomicAdd(dst + 0, (c0.x - r0.x) * s[0]);
    atomicAdd(dst + 1, (c0.y - r0.y) * s[1]);
    atomicAdd(dst + 2, (c0.z - r0.z) * s[2]);
    atomicAdd(dst + 3, (c0.w - r0.w) * s[3]);
    atomicAdd(dst + 4, (c1.x - r1.x) * s[4]);
    atomicAdd(dst + 5, (c1.y - r1.y) * s[5]);
    atomicAdd(dst + 6, (c1.z - r1.z) * s[6]);
    atomicAdd(dst + 7, (c1.w - r1.w) * s[7]);
}

__global__ __launch_bounds__(256) void fb_node_update_kernel(
    float* __restrict__ out, float* __restrict__ scattered,
    const float* __restrict__ Wf, int N)
{
    int n = blockIdx.x * blockDim.x + threadIdx.x;
    if (n >= N) return;
    float sc[D_FEAT];
    float4* sp = (float4*)(scattered + (size_t)n * D_FEAT);
    float4 a = sp[0], b = sp[1];
    sc[0] = a.x; sc[1] = a.y; sc[2] = a.z; sc[3] = a.w;
    sc[4] = b.x; sc[5] = b.y; sc[6] = b.z; sc[7] = b.w;
    sp[0] = make_float4(0.f, 0.f, 0.f, 0.f);
    sp[1] = make_float4(0.f, 0.f, 0.f, 0.f);
    float4* op = (float4*)(out + (size_t)n * D_FEAT);
    float4 o0 = op[0], o1 = op[1];
    float o[D_FEAT] = {o0.x, o0.y, o0.z, o0.w, o1.x, o1.y, o1.z, o1.w};
#pragma unroll
    for (int i = 0; i < D_FEAT; ++i) {
        float acc = 0.f;
#pragma unroll
        for (int j = 0; j < D_FEAT; ++j)
            acc = fmaf(sc[j], Wf[i * D_FEAT + j], acc);
        o[i] += acc;
    }
    op[0] = make_float4(o[0], o[1], o[2], o[3]);
    op[1] = make_float4(o[4], o[5], o[6], o[7]);
}

// ---------------------------------------------------------------------------
extern "C" void kernel_launch(void* const* d_in, const int* in_sizes, int n_in,
                              void* d_out, int out_size, void* d_ws, size_t ws_size,
                              hipStream_t stream) {
    const float* x_s       = (const float*)d_in[0];
    const float* x_d       = (const float*)d_in[1];
    const float* edge_attr = (const float*)d_in[2];
    const float* W1        = (const float*)d_in[3];
    const float* b1        = (const float*)d_in[4];
    const float* W2        = (const float*)d_in[5];
    const float* b2        = (const float*)d_in[6];
    const float* Wf0       = (const float*)d_in[7];
    const float* Wf1       = (const float*)d_in[8];
    const float* Wf2       = (const float*)d_in[9];
    const int*   ei        = (const int*)d_in[10];

    int N = in_sizes[1] / D_FEAT;
    int E = in_sizes[10] / 2;

    float* out = (float*)d_out;

    // ---- workspace layout (counts8 + done first: zeroed by one memset) ----
    size_t off = 0;
    auto carve = [&](size_t bytes) { size_t p = off; off = (off + bytes + 255) & ~255ULL; return p; };
    size_t o_counts  = carve((size_t)NSUB * N * 4);
    size_t o_done    = carve(4);
    const size_t zero_len = off;                        // counts8 + done
    size_t o_offsets = carve((size_t)(N + 1) * 4);
    size_t o_cursor  = carve((size_t)(N + 1) * 4);
    size_t o_bsums   = carve(256 * 4);
    size_t o_bufA    = carve((size_t)N * D_FEAT * 4);
    size_t o_recs    = carve((size_t)E * 16);
    const size_t need_base = off;                       // tier B
    size_t o_PR      = carve((size_t)N * HIDDEN * 2);   // fp16
    size_t o_PC      = carve((size_t)N * HIDDEN * 2);   // fp16
    const size_t need_full = off;                       // tier A

    dim3 blk(256);
    dim3 gE((E + 255) / 256);
    dim3 gN((N + 255) / 256);

    if (ws_size >= need_base) {
        char* ws = (char*)d_ws;
        int*   counts8 = (int*)(ws + o_counts);
        int*   done    = (int*)(ws + o_done);
        int*   offsets = (int*)(ws + o_offsets);
        int*   cursor  = (int*)(ws + o_cursor);
        int*   bsums   = (int*)(ws + o_bsums);
        float* bufA    = (float*)(ws + o_bufA);
        uint4v* recs   = (uint4v*)(ws + o_recs);

        const int NB = (N + SCAN_CHUNK - 1) / SCAN_CHUNK;

        hipMemsetAsync(ws, 0, zero_len, stream);  // counts8 + done

        if (ws_size >= need_full) {
            __half* PRh = (__half*)(ws + o_PR);
            __half* PCh = (__half*)(ws + o_PC);
            // K1: hist (4 edges/thread) + proj fused; grid covers max(E/4, N)
            int nth = (E + 3) / 4;
            if (nth < N) nth = N;
            hist_proj_kernel<<<dim3((nth + 255) / 256), blk, 0, stream>>>(
                ei, E, N, counts8, x_s, x_d, W1, b1, Wf0, PRh, PCh, out);
            scan_local_kernel<<<dim3(NB), blk, 0, stream>>>(
                counts8, offsets, bsums, done, N, NB);
            scan_add_kernel<<<dim3((N + 256) / 256), blk, 0, stream>>>(
                offsets, cursor, bsums, N, E);
            mlp_scatter_proj_kernel<<<gE, blk, 0, stream>>>(
                PRh, PCh, edge_attr, W1, W2, b2, ei, E, cursor, recs);
        } else {
            hist_kernel<<<gE, blk, 0, stream>>>(ei, E, N, counts8);
            scan_local_kernel<<<dim3(NB), blk, 0, stream>>>(
                counts8, offsets, bsums, done, N, NB);
            scan_add_kernel<<<dim3((N + 256) / 256), blk, 0, stream>>>(
                offsets, cursor, bsums, N, E);
            node_init_kernel<<<gN, blk, 0, stream>>>(x_d, Wf0, out, N);
            mlp_scatter_direct_kernel<<<gE, blk, 0, stream>>>(
                x_s, x_d, edge_attr, W1, b1, W2, b2, ei, E, cursor, recs);
        }

        dim3 gC((N + 3) / 4);
        csr_step_kernel<<<gC, blk, 0, stream>>>(out, bufA, offsets, recs, Wf1, N);
        csr_step_kernel<<<gC, blk, 0, stream>>>(bufA, out, offsets, recs, Wf2, N);
    } else {
        // tier C: fused atomic path, needs only N*8 floats
        float* scattered = (float*)d_ws;
        fb_node_init_kernel<<<gN, blk, 0, stream>>>(x_d, Wf0, out, scattered, N);
        for (int k = 0; k < 2; ++k) {
            const float* Wfk = (k == 0) ? Wf1 : Wf2;
            fb_edge_step_kernel<<<gE, blk, 0, stream>>>(
                x_s, x_d, edge_attr, W1, b1, W2, b2, out, ei, E, scattered);
            fb_node_update_kernel<<<gN, blk, 0, stream>>>(out, scattered, Wfk, N);
        }
    }
}